// Round 2
// baseline (973.858 us; speedup 1.0000x reference)
//
#include <hip/hip_runtime.h>
#include <stdint.h>
#include <stddef.h>

typedef __bf16 bf16;
typedef __attribute__((ext_vector_type(8))) __bf16 bf16x8;
typedef __attribute__((ext_vector_type(4))) __bf16 bf16x4;
typedef __attribute__((ext_vector_type(4))) float floatx4;

#define DEV static __device__ __forceinline__

// async global->LDS, 16B per lane. LDS dest is wave-uniform base + lane*16,
// which our chunk layout guarantees (chunk id == tid + i*256).
DEV void async_load16(const void* g, void* l) {
  __builtin_amdgcn_global_load_lds(
      (__attribute__((address_space(1))) void*)(g),
      (__attribute__((address_space(3))) void*)(l),
      16, 0, 0);
}

DEV float bf16lo_to_f(uint32_t pv) {
  uint32_t b = pv << 16; float f; __builtin_memcpy(&f, &b, 4); return f;
}
DEV float bf16hi_to_f(uint32_t pv) {
  uint32_t b = pv & 0xffff0000u; float f; __builtin_memcpy(&f, &b, 4); return f;
}

// ---------------------------------------------------------------------------
// fp32 -> bf16 convert (weights), 4 elements/thread
// ---------------------------------------------------------------------------
__global__ __launch_bounds__(256)
void f2bf_kernel(const float* __restrict__ in, bf16* __restrict__ out, int n4)
{
  int i = blockIdx.x * 256 + threadIdx.x;
  if (i < n4) {
    float4 v = ((const float4*)in)[i];
    bf16x4 o = { (bf16)v.x, (bf16)v.y, (bf16)v.z, (bf16)v.w };
    ((bf16x4*)out)[i] = o;
  }
}

// ---------------------------------------------------------------------------
// RMSNorm: one 256-thread block per row of 1024, bf16 output
// ---------------------------------------------------------------------------
__global__ __launch_bounds__(256)
void rmsnorm_kernel(const float* __restrict__ x, const float* __restrict__ w,
                    bf16* __restrict__ xn)
{
  const int row = blockIdx.x;
  const int tid = threadIdx.x;
  float4 v = ((const float4*)(x + (size_t)row * 1024))[tid];
  float ss = v.x * v.x + v.y * v.y + v.z * v.z + v.w * v.w;
  #pragma unroll
  for (int off = 1; off < 64; off <<= 1)
    ss += __shfl_xor(ss, off, 64);
  __shared__ float red[4];
  if ((tid & 63) == 0) red[tid >> 6] = ss;
  __syncthreads();
  float tot = red[0] + red[1] + red[2] + red[3];
  float rms = rsqrtf(tot * (1.0f / 1024.0f) + 1e-6f);
  float4 wv = ((const float4*)w)[tid];
  bf16x4 o;
  o[0] = (bf16)(v.x * rms * wv.x);
  o[1] = (bf16)(v.y * rms * wv.y);
  o[2] = (bf16)(v.z * rms * wv.z);
  o[3] = (bf16)(v.w * rms * wv.w);
  ((bf16x4*)(xn + (size_t)row * 1024))[tid] = o;
}

// ---------------------------------------------------------------------------
// bf16 GEMM, C = A(MxK) * B(NxK)^T, 128x128 tile, BK=64, 4 waves,
// each wave 64x64 via 4x4 grid of 16x16x32 MFMA. XOR-swizzled LDS.
// MODE 1: fused epilogue writes interleaved {s=1-sigmoid, b=silu} bf16 pairs
// MODE 2: fused bias + residual epilogue -> fp32 out
// ---------------------------------------------------------------------------
template <int MODE>
__global__ __launch_bounds__(256)
void gemm_bt_kernel(const bf16* __restrict__ A, const bf16* __restrict__ B,
                    int N, int K, int numNt,
                    bf16* __restrict__ sb, float* __restrict__ out,
                    const float* __restrict__ bias,
                    const float* __restrict__ resid)
{
  __shared__ bf16 ldsA[128 * 64];
  __shared__ bf16 ldsB[128 * 64];

  // L2-locality block swizzle: groups of 16 m-tiles x all n-tiles
  const int GROUP_M = 16;
  int bid = blockIdx.x;
  int per_group = GROUP_M * numNt;
  int group = bid / per_group;
  int rem = bid - group * per_group;
  int mt = group * GROUP_M + (rem % GROUP_M);
  int nt = rem / GROUP_M;
  const int m0 = mt * 128, n0 = nt * 128;

  const int tid  = threadIdx.x;
  const int lane = tid & 63;
  const int wave = tid >> 6;
  const int wm   = (wave & 1) * 64;
  const int wn   = (wave >> 1) * 64;
  const int l15  = lane & 15;
  const int quad = lane >> 4;

  floatx4 acc[4][4];
  #pragma unroll
  for (int i = 0; i < 4; ++i)
    #pragma unroll
    for (int j = 0; j < 4; ++j)
      acc[i][j] = (floatx4){0.f, 0.f, 0.f, 0.f};

  for (int kt = 0; kt < K; kt += 64) {
    // stage A+B tiles: 16B chunks, chunk c holds (row = c>>3, kgroup (c&7)^(row&7))
    #pragma unroll
    for (int i = 0; i < 4; ++i) {
      int c   = tid + i * 256;
      int row = c >> 3;
      int kgg = (c & 7) ^ (row & 7);
      async_load16(A + (size_t)(m0 + row) * K + kt + kgg * 8, &ldsA[c * 8]);
      async_load16(B + (size_t)(n0 + row) * K + kt + kgg * 8, &ldsB[c * 8]);
    }
    __syncthreads();   // includes vmcnt(0) drain of global_load_lds
    #pragma unroll
    for (int ks = 0; ks < 2; ++ks) {
      bf16x8 af[4], bfr[4];
      #pragma unroll
      for (int i = 0; i < 4; ++i) {
        int row = wm + i * 16 + l15;
        int kg  = ks * 4 + quad;
        af[i]  = *(const bf16x8*)&ldsA[(row * 8 + (kg ^ (row & 7))) * 8];
        int col = wn + i * 16 + l15;
        bfr[i] = *(const bf16x8*)&ldsB[(col * 8 + (kg ^ (col & 7))) * 8];
      }
      #pragma unroll
      for (int i = 0; i < 4; ++i)
        #pragma unroll
        for (int j = 0; j < 4; ++j)
          acc[i][j] = __builtin_amdgcn_mfma_f32_16x16x32_bf16(af[i], bfr[j], acc[i][j], 0, 0, 0);
    }
    __syncthreads();
  }

  // epilogue. C/D layout: col = lane&15, row = quad*4 + reg
  #pragma unroll
  for (int i = 0; i < 4; ++i) {
    #pragma unroll
    for (int j = 0; j < 4; ++j) {
      #pragma unroll
      for (int r = 0; r < 4; ++r) {
        int row = m0 + wm + i * 16 + quad * 4 + r;
        int col = n0 + wn + j * 16 + l15;
        float v = acc[i][j][r];
        if (MODE == 1) {
          v += bias[col];
          if (col < 2048) {
            // s = 1 - sigmoid(v) = 1/(1+exp(v)), computed without cancellation
            sb[((size_t)row * 2048 + col) * 2] = (bf16)(1.0f / (1.0f + __expf(v)));
          } else {
            // b = silu(v)
            sb[((size_t)row * 2048 + (col - 2048)) * 2 + 1] =
                (bf16)(v / (1.0f + __expf(-v)));
          }
        } else {
          v += bias[col] + resid[(size_t)row * N + col];
          out[(size_t)row * N + col] = v;
        }
      }
    }
  }
}

// ---------------------------------------------------------------------------
// Chunked scan over BSl sequences of N=8192 (16 chunks x 512).
// sb: interleaved {s=1-a, b} bf16 pairs, one uint32 per element.
// ---------------------------------------------------------------------------
__global__ __launch_bounds__(256)
void scan_phase1(const uint32_t* __restrict__ sb,
                 float* __restrict__ Ac, float* __restrict__ Bc)
{
  int g = blockIdx.x * 256 + threadIdx.x;    // [seq][chunk][e]
  int e     = g & 2047;
  int chunk = (g >> 11) & 15;
  int seq   = g >> 15;
  size_t base = ((size_t)(seq * 8192 + chunk * 512)) * 2048 + e;
  float A = 1.0f, Bv = 0.0f;
  #pragma unroll 8
  for (int n = 0; n < 512; ++n) {
    uint32_t pv = sb[base + (size_t)n * 2048];
    float a = 1.0f - bf16lo_to_f(pv);
    float b = bf16hi_to_f(pv);
    A *= a;
    Bv = a * Bv + b;
  }
  Ac[g] = A;
  Bc[g] = Bv;
}

__global__ __launch_bounds__(256)
void scan_phase2(const float* __restrict__ Ac, const float* __restrict__ Bc,
                 const float* __restrict__ h_prev,
                 float* __restrict__ carry, float* __restrict__ h_last)
{
  int g = blockIdx.x * 256 + threadIdx.x;    // seq*2048 + e
  int e = g & 2047;
  int seq = g >> 11;
  float h = h_prev[g];
  #pragma unroll
  for (int c = 0; c < 16; ++c) {
    size_t idx = ((size_t)(seq * 16 + c)) * 2048 + e;
    carry[idx] = h;
    h = Ac[idx] * h + Bc[idx];
  }
  h_last[g] = h;
}

__global__ __launch_bounds__(256)
void scan_phase3(const uint32_t* __restrict__ sb,
                 const float* __restrict__ carry, bf16* __restrict__ h_out)
{
  int g = blockIdx.x * 256 + threadIdx.x;
  int e     = g & 2047;
  int chunk = (g >> 11) & 15;
  int seq   = g >> 15;
  float h = carry[((size_t)(seq * 16 + chunk)) * 2048 + e];
  size_t base = ((size_t)(seq * 8192 + chunk * 512)) * 2048 + e;
  #pragma unroll 8
  for (int n = 0; n < 512; ++n) {
    uint32_t pv = sb[base + (size_t)n * 2048];
    float a = 1.0f - bf16lo_to_f(pv);
    float b = bf16hi_to_f(pv);
    h = a * h + b;
    h_out[base + (size_t)n * 2048] = (bf16)h;
  }
}

// ---------------------------------------------------------------------------
extern "C" void kernel_launch(void* const* d_in, const int* in_sizes, int n_in,
                              void* d_out, int out_size, void* d_ws, size_t ws_size,
                              hipStream_t stream)
{
  const float* x      = (const float*)d_in[0];   // (4, 8192, 1024)
  const float* h_prev = (const float*)d_in[1];   // (4, 2048)
  const float* norm_w = (const float*)d_in[2];   // (1024,)
  const float* W_in   = (const float*)d_in[3];   // (4096, 1024)
  const float* b_in   = (const float*)d_in[4];   // (4096,)
  const float* W_out  = (const float*)d_in[5];   // (1024, 2048)
  const float* b_out  = (const float*)d_in[6];   // (1024,)

  float* out    = (float*)d_out;                 // 33554432 fp32
  float* h_last = out + (size_t)33554432;        // + 8192 fp32

  // ws layout sized for BSl sequences per pass. Full (BSl=4) needs ~462 MB;
  // fallback (BSl=1, 4 passes) needs ~125 MB. Branch on ws_size is constant
  // across calls -> graph-capture safe.
  int BSl = 4, passes = 1;
  {
    size_t need4 = 14155776 + (size_t)4 * 8192 * 2048 * 4
                            + (size_t)4 * 8192 * 1024 * 2
                            + (size_t)4 * 8192 * 2048 * 2;
    if (ws_size < need4) { BSl = 1; passes = 4; }
  }
  const size_t Mrows = (size_t)BSl * 8192;
  char* ws = (char*)d_ws;
  bf16*  Win_b  = (bf16*)(ws);                       // 8 MB
  bf16*  Wout_b = (bf16*)(ws + 8388608);             // 4 MB
  size_t acN    = (size_t)BSl * 16 * 2048;           // chunk aggregates
  float* Ac     = (float*)(ws + 12582912);
  float* Bc     = (float*)(ws + 12582912 + acN * 4);
  float* carry  = (float*)(ws + 12582912 + acN * 8);
  char*  p0     = ws + 12582912 + acN * 12;
  bf16*  sb     = (bf16*)(p0);                       // Mrows*2048*4 B
  bf16*  xn     = (bf16*)(p0 + Mrows * 2048 * 4);    // Mrows*1024*2 B
  bf16*  h_arr  = (bf16*)(p0 + Mrows * 2048 * 4 + Mrows * 1024 * 2);

  f2bf_kernel<<<4096, 256, 0, stream>>>(W_in, Win_b, 4194304 / 4);
  f2bf_kernel<<<2048, 256, 0, stream>>>(W_out, Wout_b, 2097152 / 4);

  for (int p = 0; p < passes; ++p) {
    const float* xp = x + (size_t)p * Mrows * 1024;

    rmsnorm_kernel<<<(int)Mrows, 256, 0, stream>>>(xp, norm_w, xn);

    // GEMM1: (Mrows x 1024) x (4096 x 1024)^T, fused sigmoid/silu -> sb pairs
    int numMt = (int)(Mrows / 128);
    gemm_bt_kernel<1><<<numMt * 32, 256, 0, stream>>>(
        xn, Win_b, 4096, 1024, 32, sb, nullptr, b_in, nullptr);

    scan_phase1<<<BSl * 128, 256, 0, stream>>>((const uint32_t*)sb, Ac, Bc);
    scan_phase2<<<BSl * 8, 256, 0, stream>>>(Ac, Bc, h_prev + (size_t)p * BSl * 2048,
                                             carry, h_last + (size_t)p * BSl * 2048);
    scan_phase3<<<BSl * 128, 256, 0, stream>>>((const uint32_t*)sb, carry, h_arr);

    // GEMM2: (Mrows x 2048) x (1024 x 2048)^T, fused bias + residual
    gemm_bt_kernel<2><<<numMt * 8, 256, 0, stream>>>(
        h_arr, Wout_b, 1024, 2048, 8, nullptr, out + (size_t)p * Mrows * 1024,
        b_out, xp);
  }
}

// Round 3
// 965.356 us; speedup vs baseline: 1.0088x; 1.0088x over previous
//
#include <hip/hip_runtime.h>
#include <stdint.h>
#include <stddef.h>

typedef __bf16 bf16;
typedef __attribute__((ext_vector_type(8))) __bf16 bf16x8;
typedef __attribute__((ext_vector_type(4))) __bf16 bf16x4;
typedef __attribute__((ext_vector_type(4))) float floatx4;

#define DEV static __device__ __forceinline__

// async global->LDS, 16B per lane. LDS dest is wave-uniform base + lane*16.
DEV void async_load16(const void* g, void* l) {
  __builtin_amdgcn_global_load_lds(
      (__attribute__((address_space(1))) void*)(g),
      (__attribute__((address_space(3))) void*)(l),
      16, 0, 0);
}

DEV float bf16lo_to_f(uint32_t pv) {
  uint32_t b = pv << 16; float f; __builtin_memcpy(&f, &b, 4); return f;
}
DEV float bf16hi_to_f(uint32_t pv) {
  uint32_t b = pv & 0xffff0000u; float f; __builtin_memcpy(&f, &b, 4); return f;
}

// W_in row permutation: new row c holds logical channel p = (c>>5)*16 + (c&15),
// s-half if (c>>4)&1 == 0 else b-half (orig row p + 2048).
DEV int win_orig_row(int c) {
  int jt16 = c >> 4;
  int is_b = jt16 & 1;
  int p    = (jt16 >> 1) * 16 + (c & 15);
  return p + is_b * 2048;
}

// ---------------------------------------------------------------------------
// fp32 -> bf16 convert (generic, for W_out)
// ---------------------------------------------------------------------------
__global__ __launch_bounds__(256)
void f2bf_kernel(const float* __restrict__ in, bf16* __restrict__ out, int n4)
{
  int i = blockIdx.x * 256 + threadIdx.x;
  if (i < n4) {
    float4 v = ((const float4*)in)[i];
    bf16x4 o = { (bf16)v.x, (bf16)v.y, (bf16)v.z, (bf16)v.w };
    ((bf16x4*)out)[i] = o;
  }
}

// fp32 -> bf16 convert of W_in with row permutation (one block per new row)
__global__ __launch_bounds__(256)
void f2bf_win_perm(const float* __restrict__ in, bf16* __restrict__ out)
{
  int c = blockIdx.x;                    // new row 0..4095
  int orig = win_orig_row(c);
  float4 v = ((const float4*)(in + (size_t)orig * 1024))[threadIdx.x];
  bf16x4 o = { (bf16)v.x, (bf16)v.y, (bf16)v.z, (bf16)v.w };
  ((bf16x4*)(out + (size_t)c * 1024))[threadIdx.x] = o;
}

__global__ __launch_bounds__(256)
void bias_perm_kernel(const float* __restrict__ b_in, float* __restrict__ biasP)
{
  int c = blockIdx.x * 256 + threadIdx.x;   // 0..4095
  biasP[c] = b_in[win_orig_row(c)];
}

// ---------------------------------------------------------------------------
// RMSNorm: one 256-thread block per row of 1024, bf16 output
// ---------------------------------------------------------------------------
__global__ __launch_bounds__(256)
void rmsnorm_kernel(const float* __restrict__ x, const float* __restrict__ w,
                    bf16* __restrict__ xn)
{
  const int row = blockIdx.x;
  const int tid = threadIdx.x;
  float4 v = ((const float4*)(x + (size_t)row * 1024))[tid];
  float ss = v.x * v.x + v.y * v.y + v.z * v.z + v.w * v.w;
  #pragma unroll
  for (int off = 1; off < 64; off <<= 1)
    ss += __shfl_xor(ss, off, 64);
  __shared__ float red[4];
  if ((tid & 63) == 0) red[tid >> 6] = ss;
  __syncthreads();
  float tot = red[0] + red[1] + red[2] + red[3];
  float rms = rsqrtf(tot * (1.0f / 1024.0f) + 1e-6f);
  float4 wv = ((const float4*)w)[tid];
  bf16x4 o;
  o[0] = (bf16)(v.x * rms * wv.x);
  o[1] = (bf16)(v.y * rms * wv.y);
  o[2] = (bf16)(v.z * rms * wv.z);
  o[3] = (bf16)(v.w * rms * wv.w);
  ((bf16x4*)(xn + (size_t)row * 1024))[tid] = o;
}

// ---------------------------------------------------------------------------
// bf16 GEMM, C = A(MxK) * B(NxK)^T, 128x128 tile, BK=64, 4 waves,
// each wave 64x64 via 4x4 grid of 16x16x32 MFMA. XOR-swizzled LDS.
// MODE 1: paired epilogue — adjacent j-tiles hold (s-preact, b-preact) of the
//         same logical channels (via W_in row permutation); packs
//         {s=1-sigmoid, b=silu} as bf16x2 into ONE coalesced dword store.
// MODE 2: fused bias + residual epilogue -> fp32 out
// ---------------------------------------------------------------------------
template <int MODE>
__global__ __launch_bounds__(256)
void gemm_bt_kernel(const bf16* __restrict__ A, const bf16* __restrict__ B,
                    int N, int K, int numNt,
                    uint32_t* __restrict__ sbw, float* __restrict__ out,
                    const float* __restrict__ bias,
                    const float* __restrict__ resid)
{
  __shared__ bf16 ldsA[128 * 64];
  __shared__ bf16 ldsB[128 * 64];

  const int GROUP_M = 16;
  int bid = blockIdx.x;
  int per_group = GROUP_M * numNt;
  int group = bid / per_group;
  int rem = bid - group * per_group;
  int mt = group * GROUP_M + (rem % GROUP_M);
  int nt = rem / GROUP_M;
  const int m0 = mt * 128, n0 = nt * 128;

  const int tid  = threadIdx.x;
  const int lane = tid & 63;
  const int wave = tid >> 6;
  const int wm   = (wave & 1) * 64;
  const int wn   = (wave >> 1) * 64;
  const int l15  = lane & 15;
  const int quad = lane >> 4;

  floatx4 acc[4][4];
  #pragma unroll
  for (int i = 0; i < 4; ++i)
    #pragma unroll
    for (int j = 0; j < 4; ++j)
      acc[i][j] = (floatx4){0.f, 0.f, 0.f, 0.f};

  for (int kt = 0; kt < K; kt += 64) {
    #pragma unroll
    for (int i = 0; i < 4; ++i) {
      int c   = tid + i * 256;
      int row = c >> 3;
      int kgg = (c & 7) ^ (row & 7);
      async_load16(A + (size_t)(m0 + row) * K + kt + kgg * 8, &ldsA[c * 8]);
      async_load16(B + (size_t)(n0 + row) * K + kt + kgg * 8, &ldsB[c * 8]);
    }
    __syncthreads();
    #pragma unroll
    for (int ks = 0; ks < 2; ++ks) {
      bf16x8 af[4], bfr[4];
      #pragma unroll
      for (int i = 0; i < 4; ++i) {
        int row = wm + i * 16 + l15;
        int kg  = ks * 4 + quad;
        af[i]  = *(const bf16x8*)&ldsA[(row * 8 + (kg ^ (row & 7))) * 8];
        int col = wn + i * 16 + l15;
        bfr[i] = *(const bf16x8*)&ldsB[(col * 8 + (kg ^ (col & 7))) * 8];
      }
      #pragma unroll
      for (int i = 0; i < 4; ++i)
        #pragma unroll
        for (int j = 0; j < 4; ++j)
          acc[i][j] = __builtin_amdgcn_mfma_f32_16x16x32_bf16(af[i], bfr[j], acc[i][j], 0, 0, 0);
    }
    __syncthreads();
  }

  // epilogue. C/D layout: col = lane&15, row = quad*4 + reg
  if (MODE == 1) {
    #pragma unroll
    for (int i = 0; i < 4; ++i) {
      #pragma unroll
      for (int pair = 0; pair < 2; ++pair) {
        int j0 = pair * 2;
        float bs = bias[n0 + wn + j0 * 16 + l15];
        float bb = bias[n0 + wn + j0 * 16 + 16 + l15];
        int ch = (n0 >> 1) + (wn >> 1) + pair * 16 + l15;  // logical channel
        #pragma unroll
        for (int r = 0; r < 4; ++r) {
          int row = m0 + wm + i * 16 + quad * 4 + r;
          float vs = acc[i][j0][r] + bs;
          float vb = acc[i][j0 + 1][r] + bb;
          // s = 1 - sigmoid(vs) = 1/(1+exp(vs))
          float s  = 1.0f / (1.0f + __expf(vs));
          // b = silu(vb) = vb * sigmoid(vb) = vb * (1 - 1/(1+exp(vb)))
          float sv = 1.0f / (1.0f + __expf(vb));
          float bv = vb - vb * sv;
          union { bf16 h[2]; uint32_t u; } pk;
          pk.h[0] = (bf16)s;
          pk.h[1] = (bf16)bv;
          sbw[(size_t)row * 2048 + ch] = pk.u;
        }
      }
    }
  } else {
    #pragma unroll
    for (int i = 0; i < 4; ++i) {
      #pragma unroll
      for (int j = 0; j < 4; ++j) {
        #pragma unroll
        for (int r = 0; r < 4; ++r) {
          int row = m0 + wm + i * 16 + quad * 4 + r;
          int col = n0 + wn + j * 16 + l15;
          float v = acc[i][j][r] + bias[col] + resid[(size_t)row * N + col];
          out[(size_t)row * N + col] = v;
        }
      }
    }
  }
}

// ---------------------------------------------------------------------------
// Chunked scan over BSl sequences of N=8192: 32 chunks x 256 steps.
// sb: interleaved {s=1-a, b} bf16 pairs, one uint32 per element.
// ---------------------------------------------------------------------------
__global__ __launch_bounds__(256)
void scan_phase1(const uint32_t* __restrict__ sb,
                 float* __restrict__ Ac, float* __restrict__ Bc)
{
  int g = blockIdx.x * 256 + threadIdx.x;    // [seq][chunk][e]
  int e     = g & 2047;
  int chunk = (g >> 11) & 31;
  int seq   = g >> 16;
  size_t base = ((size_t)(seq * 8192 + chunk * 256)) * 2048 + e;
  float A = 1.0f, Bv = 0.0f;
  #pragma unroll 8
  for (int n = 0; n < 256; ++n) {
    uint32_t pv = sb[base + (size_t)n * 2048];
    float a = 1.0f - bf16lo_to_f(pv);
    float b = bf16hi_to_f(pv);
    A *= a;
    Bv = a * Bv + b;
  }
  Ac[g] = A;
  Bc[g] = Bv;
}

__global__ __launch_bounds__(256)
void scan_phase2(const float* __restrict__ Ac, const float* __restrict__ Bc,
                 const float* __restrict__ h_prev,
                 float* __restrict__ carry, float* __restrict__ h_last)
{
  int g = blockIdx.x * 256 + threadIdx.x;    // seq*2048 + e
  int e = g & 2047;
  int seq = g >> 11;
  float h = h_prev[g];
  #pragma unroll
  for (int c = 0; c < 32; ++c) {
    size_t idx = ((size_t)(seq * 32 + c)) * 2048 + e;
    carry[idx] = h;
    h = Ac[idx] * h + Bc[idx];
  }
  h_last[g] = h;
}

__global__ __launch_bounds__(256)
void scan_phase3(const uint32_t* __restrict__ sb,
                 const float* __restrict__ carry, bf16* __restrict__ h_out)
{
  int g = blockIdx.x * 256 + threadIdx.x;
  int e     = g & 2047;
  int chunk = (g >> 11) & 31;
  int seq   = g >> 16;
  float h = carry[((size_t)(seq * 32 + chunk)) * 2048 + e];
  size_t base = ((size_t)(seq * 8192 + chunk * 256)) * 2048 + e;
  #pragma unroll 8
  for (int n = 0; n < 256; ++n) {
    uint32_t pv = sb[base + (size_t)n * 2048];
    float a = 1.0f - bf16lo_to_f(pv);
    float b = bf16hi_to_f(pv);
    h = a * h + b;
    h_out[base + (size_t)n * 2048] = (bf16)h;
  }
}

// ---------------------------------------------------------------------------
extern "C" void kernel_launch(void* const* d_in, const int* in_sizes, int n_in,
                              void* d_out, int out_size, void* d_ws, size_t ws_size,
                              hipStream_t stream)
{
  const float* x      = (const float*)d_in[0];   // (4, 8192, 1024)
  const float* h_prev = (const float*)d_in[1];   // (4, 2048)
  const float* norm_w = (const float*)d_in[2];   // (1024,)
  const float* W_in   = (const float*)d_in[3];   // (4096, 1024)
  const float* b_in   = (const float*)d_in[4];   // (4096,)
  const float* W_out  = (const float*)d_in[5];   // (1024, 2048)
  const float* b_out  = (const float*)d_in[6];   // (1024,)

  float* out    = (float*)d_out;                 // 33554432 fp32
  float* h_last = out + (size_t)33554432;        // + 8192 fp32

  // ws layout; full (BSl=4) needs ~463 MB, fallback BSl=1 runs 4 passes.
  int BSl = 4, passes = 1;
  {
    size_t need4 = 8388608 + 4194304 + 16384
                 + 3 * ((size_t)4 * 32 * 2048 * 4)
                 + (size_t)4 * 8192 * 2048 * 4
                 + (size_t)4 * 8192 * 1024 * 2
                 + (size_t)4 * 8192 * 2048 * 2;
    if (ws_size < need4) { BSl = 1; passes = 4; }
  }
  const size_t Mrows = (size_t)BSl * 8192;
  char* ws = (char*)d_ws;
  bf16*  Win_b  = (bf16*)(ws);                       // 8 MB (permuted rows)
  bf16*  Wout_b = (bf16*)(ws + 8388608);             // 4 MB
  float* biasP  = (float*)(ws + 12582912);           // 16 KB (permuted b_in)
  size_t acN    = (size_t)BSl * 32 * 2048;           // chunk aggregates
  char*  pa     = ws + 12599296;
  float* Ac     = (float*)(pa);
  float* Bc     = (float*)(pa + acN * 4);
  float* carry  = (float*)(pa + acN * 8);
  char*  p0     = pa + acN * 12;
  uint32_t* sbw = (uint32_t*)(p0);                   // Mrows*2048*4 B
  bf16*  xn     = (bf16*)(p0 + Mrows * 2048 * 4);    // Mrows*1024*2 B
  bf16*  h_arr  = (bf16*)(p0 + Mrows * 2048 * 4 + Mrows * 1024 * 2);

  f2bf_win_perm<<<4096, 256, 0, stream>>>(W_in, Win_b);
  f2bf_kernel<<<2048, 256, 0, stream>>>(W_out, Wout_b, 2097152 / 4);
  bias_perm_kernel<<<16, 256, 0, stream>>>(b_in, biasP);

  for (int p = 0; p < passes; ++p) {
    const float* xp = x + (size_t)p * Mrows * 1024;

    rmsnorm_kernel<<<(int)Mrows, 256, 0, stream>>>(xp, norm_w, xn);

    // GEMM1: (Mrows x 1024) x (4096 x 1024)^T, fused paired sigmoid/silu
    int numMt = (int)(Mrows / 128);
    gemm_bt_kernel<1><<<numMt * 32, 256, 0, stream>>>(
        xn, Win_b, 4096, 1024, 32, sbw, nullptr, biasP, nullptr);

    scan_phase1<<<BSl * 256, 256, 0, stream>>>(sbw, Ac, Bc);
    scan_phase2<<<BSl * 8, 256, 0, stream>>>(Ac, Bc, h_prev + (size_t)p * BSl * 2048,
                                             carry, h_last + (size_t)p * BSl * 2048);
    scan_phase3<<<BSl * 256, 256, 0, stream>>>(sbw, carry, h_arr);

    // GEMM2: (Mrows x 2048) x (1024 x 2048)^T, fused bias + residual
    gemm_bt_kernel<2><<<numMt * 8, 256, 0, stream>>>(
        h_arr, Wout_b, 1024, 2048, 8, nullptr, out + (size_t)p * Mrows * 1024,
        b_out, xp);
  }
}